// Round 12
// baseline (251.778 us; speedup 1.0000x reference)
//
#include <hip/hip_runtime.h>

// DKVMN + code2vec attention. Sizes (fixed):
// B=16 L=128 P=128 NUM_C=100 D=128 M=64 EMB=128 TE=384 CODE_W=584 NROW=10002
//
// Inputs/outputs f32. MFMA operands bf16; gather tables fp8 e4m3.
// 5 dispatches (kernel-boundary overhead dominated the 7-kernel version):
//  k_prep : ONE kernel, 3 independent block partitions:
//            [0,2048)    conv: EN/EP -> fp8 EN8/EP8; transposed bf16 WeaT/WfT/WpT
//            [2048,2074) wsmall[q][m] = softmax(k_emb[q] @ Mk^T)
//            [2074,3013) preM: PS8/PE8/PP8 = fp8((emb @ Wpt slice)*2log2e) via
//                        MFMA, reading f32 EN/EP/Wpt directly (no staging deps)
//  k_cwsm : logits via fp8 gathers (tanh identity + softmax shift-invariance,
//            pairwise-rcp) + fused l-softmax -> attn[b,l,p]
//  k_cvea : 16-row tile: code_vec gather (fp8) -> LDS vA tile -> MFMA K=512
//            -> e=sigmoid, a=tanh (k_cv+k_eawM fused; no vA round-trip)
//  k_scan : sequential memory scan, LDS-staged state; read -> fA bf16
//  k_outfin: f = tanh(fA @ WfT + b_f) (LDS) then out = sigmoid(f @ WpT + b_p)

typedef unsigned char u8;
typedef unsigned short u16;
typedef unsigned int u32;
typedef unsigned long long u64;
typedef __attribute__((ext_vector_type(8))) short short8;   // 8 bf16 (4 VGPRs)
typedef __attribute__((ext_vector_type(4))) float f32x4;    // MFMA C/D
typedef __attribute__((ext_vector_type(2))) float f32x2;

#define DEV __device__ __forceinline__
#define LOG2E 1.4426950408889634f
#define KSCALE 2.8853900817779268f   // 2*log2(e)

DEV u16 f2b(float f) {
    union { float f; u32 i; } v; v.f = f;
    u32 x = v.i;
    u32 r = (x + 0x7FFFu + ((x >> 16) & 1u)) >> 16;   // RNE
    return (u16)r;
}
DEV u16 f2bt(float f) {                         // truncate (cheap; bias << fp8 grid)
    union { float f; u32 i; } v; v.f = f;
    return (u16)(v.i >> 16);
}
DEV float nexp(float x) { return __builtin_amdgcn_exp2f(x * LOG2E); }
DEV float nrcp(float x) { return __builtin_amdgcn_rcpf(x); }
DEV float fast_tanh(float x) {
    return 1.f - 2.f * nrcp(1.f + __builtin_amdgcn_exp2f(x * (2.f * LOG2E)));
}
DEV float sigmoidf_(float x) { return nrcp(1.f + __builtin_amdgcn_exp2f(-x * LOG2E)); }
DEV f32x2 d8(u32 x, bool hi) {                 // decode 2 fp8 e4m3 -> 2 f32
    return hi ? __builtin_amdgcn_cvt_pk_f32_fp8((int)x, true)
              : __builtin_amdgcn_cvt_pk_f32_fp8((int)x, false);
}
DEV u8 e8(float x) {                           // encode f32 -> fp8 e4m3
    return (u8)(__builtin_amdgcn_cvt_pk_fp8_f32(x, x, 0, false) & 0xFF);
}

// ---------------------------------------------------------------- k_prep
// Partition A [0,2048): grid-stride conv segments (all independent of B/C).
// Partition B [2048,2074): wsmall rows (4/block, one per wave).
// Partition C [2074,3013): preM; pid = bid-2074; which = pid/313; r0 = (pid%313)*32.
__global__ void k_prep(const float* __restrict__ EN, const float* __restrict__ EP,
                       const float* __restrict__ Wpt, const float* __restrict__ bpt,
                       const float* __restrict__ We, const float* __restrict__ Wa,
                       const float* __restrict__ Wf, const float* __restrict__ Wp,
                       const float* __restrict__ Kemb, const float* __restrict__ Mk,
                       u8* __restrict__ EN8, u8* __restrict__ EP8,
                       u16* __restrict__ WeaT, u16* __restrict__ WfT,
                       u16* __restrict__ WpT, float* __restrict__ wsmall,
                       u8* __restrict__ PS8, u8* __restrict__ PE8, u8* __restrict__ PP8) {
    int bid = blockIdx.x;
    if (bid < 2048) {                               // ---- conv part
        const int NEH = 10002 * 64;     // pair count per table
        const int T0 = 2 * NEH;         // end EP pairs
        const int T1 = T0 + 65536;      // end We->WeaT
        const int T2 = T1 + 65536;      // end Wa->WeaT
        const int T3 = T2 + 32768;      // end WfT
        const int T4 = T3 + 2048;       // end WpT
        for (int i = bid * 256 + threadIdx.x; i < T4; i += 2048 * 256) {
            if (i < NEH) {
                ((u16*)EN8)[i] = (u16)__builtin_amdgcn_cvt_pk_fp8_f32(EN[2 * i], EN[2 * i + 1], 0, false);
            } else if (i < T0) {
                int j = i - NEH;
                ((u16*)EP8)[j] = (u16)__builtin_amdgcn_cvt_pk_fp8_f32(EP[2 * j], EP[2 * j + 1], 0, false);
            } else if (i < T1) {
                int w = i - T0;  int k = w >> 7, n = w & 127;
                WeaT[n * 512 + k] = f2b(We[w]);
            } else if (i < T2) {
                int w = i - T1;  int k = w >> 7, n = w & 127;
                WeaT[(128 + n) * 512 + k] = f2b(Wa[w]);
            } else if (i < T3) {
                int w = i - T2;  int k = w >> 7, n = w & 127;
                WfT[n * 256 + k] = f2b(Wf[w]);
            } else {
                int w = i - T3;  int n = w >> 7, k = w & 127;
                WpT[w] = (n < 10) ? f2b(Wp[k * 10 + n]) : (u16)0;
            }
        }
        return;
    }
    int wv = threadIdx.x >> 6, lane = threadIdx.x & 63;
    if (bid < 2074) {                               // ---- wsmall part
        int row = (bid - 2048) * 4 + wv;
        if (row >= 101) return;
        float lg = 0.f;
        for (int k = 0; k < 128; k += 8) {
            float mk8[8];
#pragma unroll
            for (int u = 0; u < 8; u++) mk8[u] = Mk[lane * 128 + k + u];
#pragma unroll
            for (int u = 0; u < 8; u++) lg = fmaf(Kemb[row * 128 + k + u], mk8[u], lg);
        }
        float mx = lg;
#pragma unroll
        for (int off = 32; off; off >>= 1) mx = fmaxf(mx, __shfl_xor(mx, off, 64));
        float ex = nexp(lg - mx);
        float sum = ex;
#pragma unroll
        for (int off = 32; off; off >>= 1) sum += __shfl_xor(sum, off, 64);
        wsmall[row * 64 + lane] = ex * nrcp(sum);
        return;
    }
    // ---- preM part: f32-direct MFMA, 32 rows x 384 cols per block
    int pid = bid - 2074;
    int which = pid / 313;
    int r0 = (pid % 313) * 32;
    int m = lane & 15, quad = lane >> 4;
    const float* src = (which == 2) ? EP : EN;
    int koff = which * 128;
    u8* dst = (which == 0) ? PS8 : (which == 1) ? PE8 : PP8;

    // A fragments from f32, RNE-packed to bf16. Rows clamped (stores masked).
    short8 a[2][4];
#pragma unroll
    for (int rt = 0; rt < 2; rt++) {
        int row = min(r0 + rt * 16 + m, 10001);
        const float* ab = src + row * 128 + quad * 8;
#pragma unroll
        for (int kc = 0; kc < 4; kc++) {
            float4 f0 = *(const float4*)(ab + kc * 32);
            float4 f1 = *(const float4*)(ab + kc * 32 + 4);
            short8 v;
            v[0] = f2b(f0.x); v[1] = f2b(f0.y); v[2] = f2b(f0.z); v[3] = f2b(f0.w);
            v[4] = f2b(f1.x); v[5] = f2b(f1.y); v[6] = f2b(f1.z); v[7] = f2b(f1.w);
            a[rt][kc] = v;
        }
    }

    for (int nt = 0; nt < 6; nt++) {
        int n0 = wv * 96 + nt * 16;
        int col = n0 + m;
        float bias = (which == 2) ? bpt[col] : 0.f;
        f32x4 acc0 = {0.f, 0.f, 0.f, 0.f};
        f32x4 acc1 = {0.f, 0.f, 0.f, 0.f};
#pragma unroll
        for (int kc = 0; kc < 4; kc++) {
            const float* bb = Wpt + (koff + kc * 32 + quad * 8) * 384 + col;
            short8 bv;
#pragma unroll
            for (int j = 0; j < 8; j++) bv[j] = f2bt(bb[j * 384]);
            acc0 = __builtin_amdgcn_mfma_f32_16x16x32_bf16(a[0][kc], bv, acc0, 0, 0, 0);
            acc1 = __builtin_amdgcn_mfma_f32_16x16x32_bf16(a[1][kc], bv, acc1, 0, 0, 0);
        }
#pragma unroll
        for (int reg = 0; reg < 4; reg++) {
            int row0 = r0 + quad * 4 + reg;
            int row1 = row0 + 16;
            if (row0 < 10002) dst[row0 * 384 + col] = e8((acc0[reg] + bias) * KSCALE);
            if (row1 < 10002) dst[row1 * 384 + col] = e8((acc1[reg] + bias) * KSCALE);
        }
    }
}

// ---------------------------------------------------------------- k_cwsm
// grid 2048 = (b,p), block 256 = 16 groups of 16 lanes. Group g: l = g+16*it,
// it<8. Lane gl covers j = gl*24..+23 (dwordx4 + dwordx2 per table). Pairwise
// rcp. Logits -> LDS, fused softmax over l, attn[b][l][p] stored directly.
__global__ void k_cwsm(const int* __restrict__ code,
                       const u8* __restrict__ PS8, const u8* __restrict__ PE8,
                       const u8* __restrict__ PP8, const float* __restrict__ Watt,
                       float* __restrict__ attn) {
    int bp = blockIdx.x;
    int b = bp >> 7, p = bp & 127;
    int tid = threadIdx.x;
    int g = tid >> 4, gl = tid & 15;
    __shared__ float lgs[128];
    __shared__ float redm[4], reds[4];

    float w24[24];
    const float4* wp = (const float4*)(Watt + gl * 24);
#pragma unroll
    for (int u = 0; u < 6; u++) {
        float4 f = wp[u];
        w24[4 * u + 0] = -2.f * f.x; w24[4 * u + 1] = -2.f * f.y;
        w24[4 * u + 2] = -2.f * f.z; w24[4 * u + 3] = -2.f * f.w;
    }

    int si[8], pi[8], ei[8];
#pragma unroll
    for (int it = 0; it < 8; it++) {
        const int* c = code + ((b * 128 + g + it * 16) * 584 + 200 + 3 * p);
        si[it] = c[0]; pi[it] = c[1]; ei[it] = c[2];
    }

    uint4 cs4, ce4, cq4; uint2 cs2, ce2, cq2;
    {
        const u8* bs = PS8 + si[0] * 384 + gl * 24;
        const u8* be = PE8 + ei[0] * 384 + gl * 24;
        const u8* bq = PP8 + pi[0] * 384 + gl * 24;
        cs4 = *(const uint4*)bs; cs2 = *(const uint2*)(bs + 16);
        ce4 = *(const uint4*)be; ce2 = *(const uint2*)(be + 16);
        cq4 = *(const uint4*)bq; cq2 = *(const uint2*)(bq + 16);
    }
#pragma unroll
    for (int it = 0; it < 8; it++) {
        uint4 ns4, ne4, nq4; uint2 ns2, ne2, nq2;
        if (it < 7) {
            const u8* bs = PS8 + si[it + 1] * 384 + gl * 24;
            const u8* be = PE8 + ei[it + 1] * 384 + gl * 24;
            const u8* bq = PP8 + pi[it + 1] * 384 + gl * 24;
            ns4 = *(const uint4*)bs; ns2 = *(const uint2*)(bs + 16);
            ne4 = *(const uint4*)be; ne2 = *(const uint2*)(be + 16);
            nq4 = *(const uint4*)bq; nq2 = *(const uint2*)(bq + 16);
        }
        u32 sv[6] = { cs4.x, cs4.y, cs4.z, cs4.w, cs2.x, cs2.y };
        u32 ev[6] = { ce4.x, ce4.y, ce4.z, ce4.w, ce2.x, ce2.y };
        u32 qv[6] = { cq4.x, cq4.y, cq4.z, cq4.w, cq2.x, cq2.y };
        float acc = 0.f;
#pragma unroll
        for (int u = 0; u < 6; u++) {
            f32x2 zl = d8(sv[u], false) + d8(ev[u], false) + d8(qv[u], false);
            f32x2 zh = d8(sv[u], true)  + d8(ev[u], true)  + d8(qv[u], true);
            float d0 = 1.f + __builtin_amdgcn_exp2f(zl.x);
            float d1 = 1.f + __builtin_amdgcn_exp2f(zl.y);
            float d2 = 1.f + __builtin_amdgcn_exp2f(zh.x);
            float d3 = 1.f + __builtin_amdgcn_exp2f(zh.y);
            float n01 = fmaf(w24[4 * u + 0], d1, w24[4 * u + 1] * d0);
            float n23 = fmaf(w24[4 * u + 2], d3, w24[4 * u + 3] * d2);
            acc = fmaf(n01, nrcp(d0 * d1), acc);
            acc = fmaf(n23, nrcp(d2 * d3), acc);
        }
        acc += __shfl_xor(acc, 1, 64);
        acc += __shfl_xor(acc, 2, 64);
        acc += __shfl_xor(acc, 4, 64);
        acc += __shfl_xor(acc, 8, 64);
        if (gl == 0) lgs[g + it * 16] = acc;
        if (it < 7) {
            cs4 = ns4; cs2 = ns2;
            ce4 = ne4; ce2 = ne2;
            cq4 = nq4; cq2 = nq2;
        }
    }
    __syncthreads();

    int lane = tid & 63, wvi = tid >> 6;
    float x = (tid < 128) ? lgs[tid] : -1e30f;
    float mx = x;
#pragma unroll
    for (int off = 32; off; off >>= 1) mx = fmaxf(mx, __shfl_xor(mx, off, 64));
    if (lane == 0) redm[wvi] = mx;
    __syncthreads();
    mx = fmaxf(redm[0], redm[1]);
    float ex = nexp(x - mx);
    float sum = ex;
#pragma unroll
    for (int off = 32; off; off >>= 1) sum += __shfl_xor(sum, off, 64);
    if (lane == 0) reds[wvi] = sum;
    __syncthreads();
    float inv = nrcp(reds[0] + reds[1]);
    if (tid < 128) attn[(b * 128 + tid) * 128 + p] = ex * inv;
}

// ---------------------------------------------------------------- k_cvea
// grid 128 (16-row tiles), block 256 = 4 waves. Phase 1: 8 half-wave units
// gather code_vec (fp8, prefetched) into LDS vA tile (row pad 520 -> 2-way-free).
// Phase 2: C[16][256] = vA @ WeaT^T via MFMA (K=512); e=sigmoid, a=tanh.
__global__ void k_cvea(const int* __restrict__ code, const float* __restrict__ attn,
                       const u8* __restrict__ EN8, const u8* __restrict__ EP8,
                       const int* __restrict__ rix, const int* __restrict__ qix,
                       const float* __restrict__ Vemb, const float* __restrict__ Kemb,
                       const u16* __restrict__ WeaT,
                       const float* __restrict__ be, const float* __restrict__ ba,
                       float* __restrict__ eb, float* __restrict__ ab,
                       u16* __restrict__ fA) {
    int rt0 = blockIdx.x * 16;
    int tid = threadIdx.x;
    int wv = tid >> 6, lane = tid & 63;
    __shared__ int sip[16][384];       // interleaved (s,path,e) per p
    __shared__ float at[16][128];
    __shared__ u16 vAL[16][520];       // 128 vemb | 384 code_vec | pad 8

    for (int idx = tid; idx < 16 * 384; idx += 256) {
        int r = idx / 384, j = idx - r * 384;
        sip[r][j] = code[(rt0 + r) * 584 + 200 + j];
    }
    for (int idx = tid; idx < 2048; idx += 256) {
        int r = idx >> 7, c = idx & 127;
        at[r][c] = attn[(rt0 + r) * 128 + c];
        vAL[r][c] = f2b(Vemb[rix[rt0 + r] * 128 + c]);
        fA[(rt0 + r) * 256 + 128 + c] = f2b(Kemb[qix[rt0 + r] * 128 + c]);
    }
    __syncthreads();

    // ---- gather phase
    int h = lane >> 5, cl = lane & 31;
    int unit = wv * 2 + h;
    int o = cl * 4;
    for (int r = unit; r < 16; r += 8) {
        float a0 = 0.f, a1 = 0.f, a2 = 0.f, a3 = 0.f;
        float b0 = 0.f, b1 = 0.f, b2 = 0.f, b3 = 0.f;
        float c0 = 0.f, c1 = 0.f, c2 = 0.f, c3 = 0.f;
        u32 cur0 = *(const u32*)(EN8 + sip[r][0] * 128 + o);
        u32 cur1 = *(const u32*)(EN8 + sip[r][2] * 128 + o);
        u32 cur2 = *(const u32*)(EP8 + sip[r][1] * 128 + o);
        for (int p = 0; p < 128; p++) {
            u32 n0, n1, n2;
            if (p < 127) {
                n0 = *(const u32*)(EN8 + sip[r][3 * p + 3] * 128 + o);
                n1 = *(const u32*)(EN8 + sip[r][3 * p + 5] * 128 + o);
                n2 = *(const u32*)(EP8 + sip[r][3 * p + 4] * 128 + o);
            }
            float w = at[r][p];
            f32x2 sl = d8(cur0, false), sh = d8(cur0, true);
            f32x2 el = d8(cur1, false), eh = d8(cur1, true);
            f32x2 pl = d8(cur2, false), ph = d8(cur2, true);
            a0 = fmaf(w, sl.x, a0); a1 = fmaf(w, sl.y, a1); a2 = fmaf(w, sh.x, a2); a3 = fmaf(w, sh.y, a3);
            b0 = fmaf(w, el.x, b0); b1 = fmaf(w, el.y, b1); b2 = fmaf(w, eh.x, b2); b3 = fmaf(w, eh.y, b3);
            c0 = fmaf(w, pl.x, c0); c1 = fmaf(w, pl.y, c1); c2 = fmaf(w, ph.x, c2); c3 = fmaf(w, ph.y, c3);
            if (p < 127) { cur0 = n0; cur1 = n1; cur2 = n2; }
        }
        // pack 4 bf16 -> u64 store per table segment
        u64 pa = (u64)f2b(a0) | ((u64)f2b(a1) << 16) | ((u64)f2b(a2) << 32) | ((u64)f2b(a3) << 48);
        u64 pb = (u64)f2b(b0) | ((u64)f2b(b1) << 16) | ((u64)f2b(b2) << 32) | ((u64)f2b(b3) << 48);
        u64 pc = (u64)f2b(c0) | ((u64)f2b(c1) << 16) | ((u64)f2b(c2) << 32) | ((u64)f2b(c3) << 48);
        *(u64*)(&vAL[r][128 + o]) = pa;
        *(u64*)(&vAL[r][256 + o]) = pb;
        *(u64*)(&vAL[r][384 + o]) = pc;
    }
    __syncthreads();

    // ---- MFMA phase: wave wv covers col-tiles wv, wv+4, wv+8, wv+12
    int m = lane & 15, quad = lane >> 4;
#pragma unroll
    for (int cti = 0; cti < 4; cti++) {
        int ct = wv + cti * 4;
        const short8* bp = (const short8*)(WeaT + (ct * 16 + m) * 512 + quad * 8);
        f32x4 acc = {0.f, 0.f, 0.f, 0.f};
#pragma unroll
        for (int kc = 0; kc < 16; kc++) {
            short8 af = *(const short8*)(&vAL[m][kc * 32 + quad * 8]);
            acc = __builtin_amdgcn_mfma_f32_16x16x32_bf16(af, bp[kc * 4], acc, 0, 0, 0);
        }
        int col = ct * 16 + m;
        bool isA = col >= 128;
        int c2 = isA ? col - 128 : col;
        float bias = isA ? ba[c2] : be[c2];
#pragma unroll
        for (int reg = 0; reg < 4; reg++) {
            int row = rt0 + quad * 4 + reg;
            float val = acc[reg] + bias;
            if (isA) ab[row * 128 + c2] = fast_tanh(val);
            else     eb[row * 128 + c2] = sigmoidf_(val);
        }
    }
}

// ---------------------------------------------------------------- k_scan
// grid 256 = b(16) x dblk(16), block 64. LDS-staged wsmall + e/a tile + q.
__global__ void k_scan(const float* __restrict__ Mv0, const float* __restrict__ eb,
                       const float* __restrict__ ab, const float* __restrict__ wsmall,
                       const int* __restrict__ qq, u16* __restrict__ fA) {
    int b = blockIdx.x >> 4, dblk = blockIdx.x & 15;
    int lane = threadIdx.x;
    int s = lane >> 3, dlo = lane & 7;
    int d = dblk * 8 + dlo;

    __shared__ float wsm[101 * 64];
    __shared__ float el[128][8];
    __shared__ float al[128][8];
    __shared__ int ql[128];

    for (int i = lane; i < 101 * 64; i += 64) wsm[i] = wsmall[i];
    for (int i = lane; i < 1024; i += 64) {
        int t = i >> 3, dl = i & 7;
        el[t][dl] = eb[(b * 128 + t) * 128 + dblk * 8 + dl];
        al[t][dl] = ab[(b * 128 + t) * 128 + dblk * 8 + dl];
    }
    for (int i = lane; i < 128; i += 64) ql[i] = qq[b * 128 + i];
    __syncthreads();

    float mv[8];
#pragma unroll
    for (int q = 0; q < 8; q++) mv[q] = Mv0[(s * 8 + q) * 128 + d];

    u16* fout = fA + (b * 128) * 256 + d;

    int qt = ql[0];
    const float4* wr = (const float4*)(wsm + qt * 64 + s * 8);
    float4 w0 = wr[0], w1 = wr[1];
    float ecur = el[0][dlo], acur = al[0][dlo];

    for (int t = 0; t < 128; t++) {
        int tn = (t < 127) ? t + 1 : 127;
        int qn = ql[tn];
        const float4* wrn = (const float4*)(wsm + qn * 64 + s * 8);
        float4 nw0 = wrn[0], nw1 = wrn[1];
        float en = el[tn][dlo], an = al[tn][dlo];

        float w[8] = { w0.x, w0.y, w0.z, w0.w, w1.x, w1.y, w1.z, w1.w };
        float rd = 0.f;
#pragma unroll
        for (int q = 0; q < 8; q++) {
            rd = fmaf(w[q], mv[q], rd);
            mv[q] = fmaf(w[q], fmaf(-mv[q], ecur, acur), mv[q]);
        }
        rd += __shfl_xor(rd, 8, 64);
        rd += __shfl_xor(rd, 16, 64);
        rd += __shfl_xor(rd, 32, 64);
        if (s == 0) fout[t * 256] = f2b(rd);

        ecur = en; acur = an; w0 = nw0; w1 = nw1;
    }
}

// ---------------------------------------------------------------- k_outfin
// grid 128, block 512 (8 waves). Wave wv computes f tile rows rt*16..+15 x cols
// wv*16..+15 (K=256 MFMA), tanh -> LDS bf16. Then wave 0: out = sigmoid(f @ WpT^T + b_p).
__global__ void k_outfin(const u16* __restrict__ fA, const u16* __restrict__ WfT,
                         const float* __restrict__ bfp, const u16* __restrict__ WpT,
                         const float* __restrict__ bp, float* __restrict__ out) {
    int rt = blockIdx.x;
    int wv = threadIdx.x >> 6, lane = threadIdx.x & 63;
    int m = lane & 15, quad = lane >> 4;
    __shared__ u16 ftile[16][128];

    const short8* ap = (const short8*)(fA + (rt * 16 + m) * 256 + quad * 8);
    const short8* bpw = (const short8*)(WfT + (wv * 16 + m) * 256 + quad * 8);
    f32x4 acc = {0.f, 0.f, 0.f, 0.f};
#pragma unroll
    for (int kc = 0; kc < 8; kc++)
        acc = __builtin_amdgcn_mfma_f32_16x16x32_bf16(ap[kc * 4], bpw[kc * 4], acc, 0, 0, 0);
    int col = wv * 16 + m;
    float bias = bfp[col];
#pragma unroll
    for (int reg = 0; reg < 4; reg++)
        ftile[quad * 4 + reg][col] = f2b(fast_tanh(acc[reg] + bias));
    __syncthreads();

    if (wv == 0) {
        f32x4 facc = {0.f, 0.f, 0.f, 0.f};
#pragma unroll
        for (int kc = 0; kc < 4; kc++) {
            short8 af = *(const short8*)(&ftile[m][kc * 32 + quad * 8]);
            short8 bf = *(const short8*)(WpT + m * 128 + kc * 32 + quad * 8);
            facc = __builtin_amdgcn_mfma_f32_16x16x32_bf16(af, bf, facc, 0, 0, 0);
        }
        if (m < 10) {
            float bias2 = bp[m];
#pragma unroll
            for (int reg = 0; reg < 4; reg++) {
                int row = rt * 16 + quad * 4 + reg;
                out[row * 10 + m] = sigmoidf_(facc[reg] + bias2);
            }
        }
    }
}

extern "C" void kernel_launch(void* const* d_in, const int* in_sizes, int n_in,
                              void* d_out, int out_size, void* d_ws, size_t ws_size,
                              hipStream_t stream) {
    const int*   code = (const int*)d_in[0];
    const int*   q    = (const int*)d_in[1];
    const int*   r    = (const int*)d_in[2];
    const float* EN   = (const float*)d_in[3];
    const float* EP   = (const float*)d_in[4];
    const float* Wpt  = (const float*)d_in[5];
    const float* bpt  = (const float*)d_in[6];
    const float* Watt = (const float*)d_in[7];
    const float* Kemb = (const float*)d_in[9];
    const float* Mk   = (const float*)d_in[10];
    const float* Mv0  = (const float*)d_in[11];
    const float* Vemb = (const float*)d_in[12];
    const float* We   = (const float*)d_in[13];
    const float* be   = (const float*)d_in[14];
    const float* Wa   = (const float*)d_in[15];
    const float* ba   = (const float*)d_in[16];
    const float* Wf   = (const float*)d_in[17];
    const float* bf_  = (const float*)d_in[18];
    const float* Wp   = (const float*)d_in[19];
    const float* bp   = (const float*)d_in[20];

    char* ws = (char*)d_ws;
    size_t off = 0;
    auto alloc = [&](size_t bytes) { void* p = ws + off; off = (off + bytes + 255) & ~255UL; return p; };
    u8*    PS8    = (u8*)alloc(10002UL * 384);
    u8*    PE8    = (u8*)alloc(10002UL * 384);
    u8*    PP8    = (u8*)alloc(10002UL * 384);
    u8*    EN8    = (u8*)alloc(10002UL * 128);
    u8*    EP8    = (u8*)alloc(10002UL * 128);
    u16*   WeaT   = (u16*)alloc(256UL * 512 * 2);
    u16*   WfT    = (u16*)alloc(128UL * 256 * 2);
    u16*   WpT    = (u16*)alloc(16UL * 128 * 2);
    float* attn   = (float*)alloc(16UL * 128 * 128 * 4);   // [b][l][p]
    u16*   fA     = (u16*)alloc(2048UL * 256 * 2);         // [read ; Kemb[q]] bf16
    float* eb     = (float*)alloc(2048UL * 128 * 4);
    float* ab     = (float*)alloc(2048UL * 128 * 4);
    float* wsmall = (float*)alloc(101UL * 64 * 4);

    k_prep<<<3013, 256, 0, stream>>>(EN, EP, Wpt, bpt, We, Wa, Wf, Wp, Kemb, Mk,
                                     EN8, EP8, WeaT, WfT, WpT, wsmall, PS8, PE8, PP8);
    k_cwsm<<<2048, 256, 0, stream>>>(code, PS8, PE8, PP8, Watt, attn);
    k_cvea<<<128, 256, 0, stream>>>(code, attn, EN8, EP8, r, q, Vemb, Kemb,
                                    WeaT, be, ba, eb, ab, fA);
    k_scan<<<256, 64, 0, stream>>>(Mv0, eb, ab, wsmall, q, fA);
    k_outfin<<<128, 512, 0, stream>>>(fA, WfT, bf_, WpT, bp, (float*)d_out);
}

// Round 13
// 222.163 us; speedup vs baseline: 1.1333x; 1.1333x over previous
//
#include <hip/hip_runtime.h>

// DKVMN + code2vec attention. Sizes (fixed):
// B=16 L=128 P=128 NUM_C=100 D=128 M=64 EMB=128 TE=384 CODE_W=584 NROW=10002
//
// Inputs/outputs f32. MFMA operands bf16; gather tables fp8 e4m3.
// 6 dispatches. (Round-12 lesson: fusing the latency-bound gather into a
// 128-block kernel collapsed occupancy 5x — gathers need 2048 blocks.)
//  k_prep : ONE kernel, 3 independent block partitions:
//            [0,2048)    conv: EN/EP -> fp8 EN8/EP8; transposed bf16 WeaT/WfT/WpT
//            [2048,2074) wsmall[q][m] = softmax(k_emb[q] @ Mk^T)
//            [2074,3013) preM: PS8/PE8/PP8 = fp8((emb @ Wpt slice)*2log2e) via
//                        MFMA reading f32 EN/EP/Wpt directly
//  k_cwsm : logits via fp8 gathers (tanh identity + softmax shift-invariance,
//            pairwise-rcp) + fused l-softmax -> attn[b,l,p]
//  k_cv   : 2048 blocks, half-wave coalesced u32 fp8 gathers -> vA bf16
//  k_eawM : e|a = act(vA @ WeaT + b) via MFMA  [2048x512]@[512x256]
//  k_scan : sequential memory scan, LDS-staged state; read -> fA bf16
//  k_outfin: f = tanh(fA @ WfT + b_f) (LDS) then out = sigmoid(f @ WpT + b_p)

typedef unsigned char u8;
typedef unsigned short u16;
typedef unsigned int u32;
typedef __attribute__((ext_vector_type(8))) short short8;   // 8 bf16 (4 VGPRs)
typedef __attribute__((ext_vector_type(4))) float f32x4;    // MFMA C/D
typedef __attribute__((ext_vector_type(2))) float f32x2;

#define DEV __device__ __forceinline__
#define LOG2E 1.4426950408889634f
#define KSCALE 2.8853900817779268f   // 2*log2(e)

DEV u16 f2b(float f) {
    union { float f; u32 i; } v; v.f = f;
    u32 x = v.i;
    u32 r = (x + 0x7FFFu + ((x >> 16) & 1u)) >> 16;   // RNE
    return (u16)r;
}
DEV u16 f2bt(float f) {                         // truncate (bias << fp8 grid)
    union { float f; u32 i; } v; v.f = f;
    return (u16)(v.i >> 16);
}
DEV float nexp(float x) { return __builtin_amdgcn_exp2f(x * LOG2E); }
DEV float nrcp(float x) { return __builtin_amdgcn_rcpf(x); }
DEV float fast_tanh(float x) {
    return 1.f - 2.f * nrcp(1.f + __builtin_amdgcn_exp2f(x * (2.f * LOG2E)));
}
DEV float sigmoidf_(float x) { return nrcp(1.f + __builtin_amdgcn_exp2f(-x * LOG2E)); }
DEV f32x2 d8(u32 x, bool hi) {                 // decode 2 fp8 e4m3 -> 2 f32
    return hi ? __builtin_amdgcn_cvt_pk_f32_fp8((int)x, true)
              : __builtin_amdgcn_cvt_pk_f32_fp8((int)x, false);
}
DEV u8 e8(float x) {                           // encode f32 -> fp8 e4m3
    return (u8)(__builtin_amdgcn_cvt_pk_fp8_f32(x, x, 0, false) & 0xFF);
}

// ---------------------------------------------------------------- k_prep
// Partition A [0,2048): grid-stride conv segments.
// Partition B [2048,2074): wsmall rows (4/block, one per wave).
// Partition C [2074,3013): preM; pid = bid-2074; which = pid/313; r0 = (pid%313)*32.
__global__ void k_prep(const float* __restrict__ EN, const float* __restrict__ EP,
                       const float* __restrict__ Wpt, const float* __restrict__ bpt,
                       const float* __restrict__ We, const float* __restrict__ Wa,
                       const float* __restrict__ Wf, const float* __restrict__ Wp,
                       const float* __restrict__ Kemb, const float* __restrict__ Mk,
                       u8* __restrict__ EN8, u8* __restrict__ EP8,
                       u16* __restrict__ WeaT, u16* __restrict__ WfT,
                       u16* __restrict__ WpT, float* __restrict__ wsmall,
                       u8* __restrict__ PS8, u8* __restrict__ PE8, u8* __restrict__ PP8) {
    int bid = blockIdx.x;
    if (bid < 2048) {                               // ---- conv part
        const int NEH = 10002 * 64;     // pair count per table
        const int T0 = 2 * NEH;         // end EP pairs
        const int T1 = T0 + 65536;      // end We->WeaT
        const int T2 = T1 + 65536;      // end Wa->WeaT
        const int T3 = T2 + 32768;      // end WfT
        const int T4 = T3 + 2048;       // end WpT
        for (int i = bid * 256 + threadIdx.x; i < T4; i += 2048 * 256) {
            if (i < NEH) {
                ((u16*)EN8)[i] = (u16)__builtin_amdgcn_cvt_pk_fp8_f32(EN[2 * i], EN[2 * i + 1], 0, false);
            } else if (i < T0) {
                int j = i - NEH;
                ((u16*)EP8)[j] = (u16)__builtin_amdgcn_cvt_pk_fp8_f32(EP[2 * j], EP[2 * j + 1], 0, false);
            } else if (i < T1) {
                int w = i - T0;  int k = w >> 7, n = w & 127;
                WeaT[n * 512 + k] = f2b(We[w]);
            } else if (i < T2) {
                int w = i - T1;  int k = w >> 7, n = w & 127;
                WeaT[(128 + n) * 512 + k] = f2b(Wa[w]);
            } else if (i < T3) {
                int w = i - T2;  int k = w >> 7, n = w & 127;
                WfT[n * 256 + k] = f2b(Wf[w]);
            } else {
                int w = i - T3;  int n = w >> 7, k = w & 127;
                WpT[w] = (n < 10) ? f2b(Wp[k * 10 + n]) : (u16)0;
            }
        }
        return;
    }
    int wv = threadIdx.x >> 6, lane = threadIdx.x & 63;
    if (bid < 2074) {                               // ---- wsmall part
        int row = (bid - 2048) * 4 + wv;
        if (row >= 101) return;
        float lg = 0.f;
        for (int k = 0; k < 128; k += 8) {
            float mk8[8];
#pragma unroll
            for (int u = 0; u < 8; u++) mk8[u] = Mk[lane * 128 + k + u];
#pragma unroll
            for (int u = 0; u < 8; u++) lg = fmaf(Kemb[row * 128 + k + u], mk8[u], lg);
        }
        float mx = lg;
#pragma unroll
        for (int off = 32; off; off >>= 1) mx = fmaxf(mx, __shfl_xor(mx, off, 64));
        float ex = nexp(lg - mx);
        float sum = ex;
#pragma unroll
        for (int off = 32; off; off >>= 1) sum += __shfl_xor(sum, off, 64);
        wsmall[row * 64 + lane] = ex * nrcp(sum);
        return;
    }
    // ---- preM part: f32-direct MFMA, 32 rows x 384 cols per block
    int pid = bid - 2074;
    int which = pid / 313;
    int r0 = (pid % 313) * 32;
    int m = lane & 15, quad = lane >> 4;
    const float* src = (which == 2) ? EP : EN;
    int koff = which * 128;
    u8* dst = (which == 0) ? PS8 : (which == 1) ? PE8 : PP8;

    short8 a[2][4];
#pragma unroll
    for (int rt = 0; rt < 2; rt++) {
        int row = min(r0 + rt * 16 + m, 10001);
        const float* ab = src + row * 128 + quad * 8;
#pragma unroll
        for (int kc = 0; kc < 4; kc++) {
            float4 f0 = *(const float4*)(ab + kc * 32);
            float4 f1 = *(const float4*)(ab + kc * 32 + 4);
            short8 v;
            v[0] = f2b(f0.x); v[1] = f2b(f0.y); v[2] = f2b(f0.z); v[3] = f2b(f0.w);
            v[4] = f2b(f1.x); v[5] = f2b(f1.y); v[6] = f2b(f1.z); v[7] = f2b(f1.w);
            a[rt][kc] = v;
        }
    }

    for (int nt = 0; nt < 6; nt++) {
        int n0 = wv * 96 + nt * 16;
        int col = n0 + m;
        float bias = (which == 2) ? bpt[col] : 0.f;
        f32x4 acc0 = {0.f, 0.f, 0.f, 0.f};
        f32x4 acc1 = {0.f, 0.f, 0.f, 0.f};
#pragma unroll
        for (int kc = 0; kc < 4; kc++) {
            const float* bb = Wpt + (koff + kc * 32 + quad * 8) * 384 + col;
            short8 bv;
#pragma unroll
            for (int j = 0; j < 8; j++) bv[j] = f2bt(bb[j * 384]);
            acc0 = __builtin_amdgcn_mfma_f32_16x16x32_bf16(a[0][kc], bv, acc0, 0, 0, 0);
            acc1 = __builtin_amdgcn_mfma_f32_16x16x32_bf16(a[1][kc], bv, acc1, 0, 0, 0);
        }
#pragma unroll
        for (int reg = 0; reg < 4; reg++) {
            int row0 = r0 + quad * 4 + reg;
            int row1 = row0 + 16;
            if (row0 < 10002) dst[row0 * 384 + col] = e8((acc0[reg] + bias) * KSCALE);
            if (row1 < 10002) dst[row1 * 384 + col] = e8((acc1[reg] + bias) * KSCALE);
        }
    }
}

// ---------------------------------------------------------------- k_cwsm
// grid 2048 = (b,p), block 256 = 16 groups of 16 lanes. Group g: l = g+16*it,
// it<8. Lane gl covers j = gl*24..+23 (dwordx4 + dwordx2 per table). Pairwise
// rcp. Logits -> LDS, fused softmax over l, attn[b][l][p] stored directly.
__global__ void k_cwsm(const int* __restrict__ code,
                       const u8* __restrict__ PS8, const u8* __restrict__ PE8,
                       const u8* __restrict__ PP8, const float* __restrict__ Watt,
                       float* __restrict__ attn) {
    int bp = blockIdx.x;
    int b = bp >> 7, p = bp & 127;
    int tid = threadIdx.x;
    int g = tid >> 4, gl = tid & 15;
    __shared__ float lgs[128];
    __shared__ float redm[4], reds[4];

    float w24[24];
    const float4* wp = (const float4*)(Watt + gl * 24);
#pragma unroll
    for (int u = 0; u < 6; u++) {
        float4 f = wp[u];
        w24[4 * u + 0] = -2.f * f.x; w24[4 * u + 1] = -2.f * f.y;
        w24[4 * u + 2] = -2.f * f.z; w24[4 * u + 3] = -2.f * f.w;
    }

    int si[8], pi[8], ei[8];
#pragma unroll
    for (int it = 0; it < 8; it++) {
        const int* c = code + ((b * 128 + g + it * 16) * 584 + 200 + 3 * p);
        si[it] = c[0]; pi[it] = c[1]; ei[it] = c[2];
    }

    uint4 cs4, ce4, cq4; uint2 cs2, ce2, cq2;
    {
        const u8* bs = PS8 + si[0] * 384 + gl * 24;
        const u8* be = PE8 + ei[0] * 384 + gl * 24;
        const u8* bq = PP8 + pi[0] * 384 + gl * 24;
        cs4 = *(const uint4*)bs; cs2 = *(const uint2*)(bs + 16);
        ce4 = *(const uint4*)be; ce2 = *(const uint2*)(be + 16);
        cq4 = *(const uint4*)bq; cq2 = *(const uint2*)(bq + 16);
    }
#pragma unroll
    for (int it = 0; it < 8; it++) {
        uint4 ns4, ne4, nq4; uint2 ns2, ne2, nq2;
        if (it < 7) {
            const u8* bs = PS8 + si[it + 1] * 384 + gl * 24;
            const u8* be = PE8 + ei[it + 1] * 384 + gl * 24;
            const u8* bq = PP8 + pi[it + 1] * 384 + gl * 24;
            ns4 = *(const uint4*)bs; ns2 = *(const uint2*)(bs + 16);
            ne4 = *(const uint4*)be; ne2 = *(const uint2*)(be + 16);
            nq4 = *(const uint4*)bq; nq2 = *(const uint2*)(bq + 16);
        }
        u32 sv[6] = { cs4.x, cs4.y, cs4.z, cs4.w, cs2.x, cs2.y };
        u32 ev[6] = { ce4.x, ce4.y, ce4.z, ce4.w, ce2.x, ce2.y };
        u32 qv[6] = { cq4.x, cq4.y, cq4.z, cq4.w, cq2.x, cq2.y };
        float acc = 0.f;
#pragma unroll
        for (int u = 0; u < 6; u++) {
            f32x2 zl = d8(sv[u], false) + d8(ev[u], false) + d8(qv[u], false);
            f32x2 zh = d8(sv[u], true)  + d8(ev[u], true)  + d8(qv[u], true);
            float d0 = 1.f + __builtin_amdgcn_exp2f(zl.x);
            float d1 = 1.f + __builtin_amdgcn_exp2f(zl.y);
            float d2 = 1.f + __builtin_amdgcn_exp2f(zh.x);
            float d3 = 1.f + __builtin_amdgcn_exp2f(zh.y);
            float n01 = fmaf(w24[4 * u + 0], d1, w24[4 * u + 1] * d0);
            float n23 = fmaf(w24[4 * u + 2], d3, w24[4 * u + 3] * d2);
            acc = fmaf(n01, nrcp(d0 * d1), acc);
            acc = fmaf(n23, nrcp(d2 * d3), acc);
        }
        acc += __shfl_xor(acc, 1, 64);
        acc += __shfl_xor(acc, 2, 64);
        acc += __shfl_xor(acc, 4, 64);
        acc += __shfl_xor(acc, 8, 64);
        if (gl == 0) lgs[g + it * 16] = acc;
        if (it < 7) {
            cs4 = ns4; cs2 = ns2;
            ce4 = ne4; ce2 = ne2;
            cq4 = nq4; cq2 = nq2;
        }
    }
    __syncthreads();

    int lane = tid & 63, wvi = tid >> 6;
    float x = (tid < 128) ? lgs[tid] : -1e30f;
    float mx = x;
#pragma unroll
    for (int off = 32; off; off >>= 1) mx = fmaxf(mx, __shfl_xor(mx, off, 64));
    if (lane == 0) redm[wvi] = mx;
    __syncthreads();
    mx = fmaxf(redm[0], redm[1]);
    float ex = nexp(x - mx);
    float sum = ex;
#pragma unroll
    for (int off = 32; off; off >>= 1) sum += __shfl_xor(sum, off, 64);
    if (lane == 0) reds[wvi] = sum;
    __syncthreads();
    float inv = nrcp(reds[0] + reds[1]);
    if (tid < 128) attn[(b * 128 + tid) * 128 + p] = ex * inv;
}

// ---------------------------------------------------------------- k_cv
// grid 2048 = (b,l), block 256 = 4 waves. Half-wave coalesced u32 fp8 gathers:
// lanes 0-31 cover row(p), lanes 32-63 row(p+4), 4 cols/lane, prefetched.
__global__ void k_cv(const int* __restrict__ code, const float* __restrict__ attn,
                     const u8* __restrict__ EN8, const u8* __restrict__ EP8,
                     const int* __restrict__ rr, const int* __restrict__ qq,
                     const float* __restrict__ Vemb, const float* __restrict__ Kemb,
                     u16* __restrict__ vA, u16* __restrict__ fA) {
    int row = blockIdx.x;
    int tid = threadIdx.x;
    int wv = tid >> 6, lane = tid & 63;
    int h = lane >> 5, cl = lane & 31;
    __shared__ int si[128], ei[128], pi[128];
    __shared__ float at[128];
    __shared__ float part[8][3][128];
    if (tid < 128) {
        const int* c = code + (row * 584 + 200);
        si[tid] = c[3 * tid]; pi[tid] = c[3 * tid + 1]; ei[tid] = c[3 * tid + 2];
        at[tid] = attn[row * 128 + tid];
    }
    if (tid < 128) {
        vA[row * 512 + tid] = f2b(Vemb[rr[row] * 128 + tid]);
    } else {
        int t2 = tid - 128;
        fA[row * 256 + 128 + t2] = f2b(Kemb[qq[row] * 128 + t2]);
    }
    __syncthreads();

    int o = cl * 4;                              // byte offset in 128-B row
    int pb = wv + h * 4;                         // this half's p base (stride 8)
    float a0 = 0.f, a1 = 0.f, a2 = 0.f, a3 = 0.f;
    float b0 = 0.f, b1 = 0.f, b2 = 0.f, b3 = 0.f;
    float c0 = 0.f, c1 = 0.f, c2 = 0.f, c3 = 0.f;

    u32 cur0, cur1, cur2;
    cur0 = *(const u32*)(EN8 + si[pb] * 128 + o);
    cur1 = *(const u32*)(EN8 + ei[pb] * 128 + o);
    cur2 = *(const u32*)(EP8 + pi[pb] * 128 + o);
#pragma unroll
    for (int it = 0; it < 16; it++) {
        int p = pb + it * 8;
        u32 n0, n1, n2;
        if (it < 15) {
            int pn = p + 8;
            n0 = *(const u32*)(EN8 + si[pn] * 128 + o);
            n1 = *(const u32*)(EN8 + ei[pn] * 128 + o);
            n2 = *(const u32*)(EP8 + pi[pn] * 128 + o);
        }
        float w = at[p];
        f32x2 sl = d8(cur0, false), sh = d8(cur0, true);
        f32x2 el = d8(cur1, false), eh = d8(cur1, true);
        f32x2 pl = d8(cur2, false), ph = d8(cur2, true);
        a0 = fmaf(w, sl.x, a0); a1 = fmaf(w, sl.y, a1); a2 = fmaf(w, sh.x, a2); a3 = fmaf(w, sh.y, a3);
        b0 = fmaf(w, el.x, b0); b1 = fmaf(w, el.y, b1); b2 = fmaf(w, eh.x, b2); b3 = fmaf(w, eh.y, b3);
        c0 = fmaf(w, pl.x, c0); c1 = fmaf(w, pl.y, c1); c2 = fmaf(w, ph.x, c2); c3 = fmaf(w, ph.y, c3);
        if (it < 15) { cur0 = n0; cur1 = n1; cur2 = n2; }
    }
    int slot = wv * 2 + h;
    part[slot][0][o + 0] = a0; part[slot][0][o + 1] = a1; part[slot][0][o + 2] = a2; part[slot][0][o + 3] = a3;
    part[slot][1][o + 0] = b0; part[slot][1][o + 1] = b1; part[slot][1][o + 2] = b2; part[slot][1][o + 3] = b3;
    part[slot][2][o + 0] = c0; part[slot][2][o + 1] = c1; part[slot][2][o + 2] = c2; part[slot][2][o + 3] = c3;
    __syncthreads();
    u16* vrow = vA + row * 512 + 128;
    for (int idx = tid; idx < 384; idx += 256) {
        int tbl = idx >> 7, col = idx & 127;
        float s = 0.f;
#pragma unroll
        for (int sl2 = 0; sl2 < 8; sl2++) s += part[sl2][tbl][col];
        vrow[idx] = f2b(s);
    }
}

// ---------------------------------------------------------------- k_eawM
// grid 512, block 256 (4 waves). C[2048][256] = vA @ WeaT^T via MFMA. K=512.
__global__ void k_eawM(const u16* __restrict__ vA, const u16* __restrict__ WeaT,
                       const float* __restrict__ be, const float* __restrict__ ba,
                       float* __restrict__ eb, float* __restrict__ ab) {
    int rt = blockIdx.x >> 2, cg = blockIdx.x & 3;
    int wv = threadIdx.x >> 6, lane = threadIdx.x & 63;
    int ct = cg * 4 + wv;
    int m = lane & 15, quad = lane >> 4;
    const short8* ap = (const short8*)(vA + (rt * 16 + m) * 512 + quad * 8);
    const short8* bp = (const short8*)(WeaT + (ct * 16 + m) * 512 + quad * 8);
    f32x4 acc = {0.f, 0.f, 0.f, 0.f};
#pragma unroll
    for (int kc = 0; kc < 16; kc++)
        acc = __builtin_amdgcn_mfma_f32_16x16x32_bf16(ap[kc * 4], bp[kc * 4], acc, 0, 0, 0);
    int col = ct * 16 + m;
    bool isA = col >= 128;
    int c2 = isA ? col - 128 : col;
    float bias = isA ? ba[c2] : be[c2];
#pragma unroll
    for (int reg = 0; reg < 4; reg++) {
        int row = rt * 16 + quad * 4 + reg;
        float val = acc[reg] + bias;
        if (isA) ab[row * 128 + c2] = fast_tanh(val);
        else     eb[row * 128 + c2] = sigmoidf_(val);
    }
}

// ---------------------------------------------------------------- k_scan
// grid 256 = b(16) x dblk(16), block 64. LDS-staged wsmall + e/a tile + q.
__global__ void k_scan(const float* __restrict__ Mv0, const float* __restrict__ eb,
                       const float* __restrict__ ab, const float* __restrict__ wsmall,
                       const int* __restrict__ qq, u16* __restrict__ fA) {
    int b = blockIdx.x >> 4, dblk = blockIdx.x & 15;
    int lane = threadIdx.x;
    int s = lane >> 3, dlo = lane & 7;
    int d = dblk * 8 + dlo;

    __shared__ float wsm[101 * 64];
    __shared__ float el[128][8];
    __shared__ float al[128][8];
    __shared__ int ql[128];

    for (int i = lane; i < 101 * 64; i += 64) wsm[i] = wsmall[i];
    for (int i = lane; i < 1024; i += 64) {
        int t = i >> 3, dl = i & 7;
        el[t][dl] = eb[(b * 128 + t) * 128 + dblk * 8 + dl];
        al[t][dl] = ab[(b * 128 + t) * 128 + dblk * 8 + dl];
    }
    for (int i = lane; i < 128; i += 64) ql[i] = qq[b * 128 + i];
    __syncthreads();

    float mv[8];
#pragma unroll
    for (int q = 0; q < 8; q++) mv[q] = Mv0[(s * 8 + q) * 128 + d];

    u16* fout = fA + (b * 128) * 256 + d;

    int qt = ql[0];
    const float4* wr = (const float4*)(wsm + qt * 64 + s * 8);
    float4 w0 = wr[0], w1 = wr[1];
    float ecur = el[0][dlo], acur = al[0][dlo];

    for (int t = 0; t < 128; t++) {
        int tn = (t < 127) ? t + 1 : 127;
        int qn = ql[tn];
        const float4* wrn = (const float4*)(wsm + qn * 64 + s * 8);
        float4 nw0 = wrn[0], nw1 = wrn[1];
        float en = el[tn][dlo], an = al[tn][dlo];

        float w[8] = { w0.x, w0.y, w0.z, w0.w, w1.x, w1.y, w1.z, w1.w };
        float rd = 0.f;
#pragma unroll
        for (int q = 0; q < 8; q++) {
            rd = fmaf(w[q], mv[q], rd);
            mv[q] = fmaf(w[q], fmaf(-mv[q], ecur, acur), mv[q]);
        }
        rd += __shfl_xor(rd, 8, 64);
        rd += __shfl_xor(rd, 16, 64);
        rd += __shfl_xor(rd, 32, 64);
        if (s == 0) fout[t * 256] = f2b(rd);

        ecur = en; acur = an; w0 = nw0; w1 = nw1;
    }
}

// ---------------------------------------------------------------- k_outfin
// grid 128, block 512 (8 waves). Wave wv computes f tile rows rt*16..+15 x cols
// wv*16..+15 (K=256 MFMA), tanh -> LDS bf16. Then wave 0: out = sigmoid(f @ WpT^T + b_p).
__global__ void k_outfin(const u16* __restrict__ fA, const u16* __restrict__ WfT,
                         const float* __restrict__ bfp, const u16* __restrict__ WpT,
                         const float* __restrict__ bp, float* __restrict__ out) {
    int rt = blockIdx.x;
    int wv = threadIdx.x >> 6, lane = threadIdx.x & 63;
    int m = lane & 15, quad = lane >> 4;
    __shared__ u16 ftile[16][128];

    const short8* ap = (const short8*)(fA + (rt * 16 + m) * 256 + quad * 8);
    const short8* bpw = (const short8*)(WfT + (wv * 16 + m) * 256 + quad * 8);
    f32x4 acc = {0.f, 0.f, 0.f, 0.f};
#pragma unroll
    for (int kc = 0; kc < 8; kc++)
        acc = __builtin_amdgcn_mfma_f32_16x16x32_bf16(ap[kc * 4], bpw[kc * 4], acc, 0, 0, 0);
    int col = wv * 16 + m;
    float bias = bfp[col];
#pragma unroll
    for (int reg = 0; reg < 4; reg++)
        ftile[quad * 4 + reg][col] = f2b(fast_tanh(acc[reg] + bias));
    __syncthreads();

    if (wv == 0) {
        f32x4 facc = {0.f, 0.f, 0.f, 0.f};
#pragma unroll
        for (int kc = 0; kc < 4; kc++) {
            short8 af = *(const short8*)(&ftile[m][kc * 32 + quad * 8]);
            short8 bf = *(const short8*)(WpT + m * 128 + kc * 32 + quad * 8);
            facc = __builtin_amdgcn_mfma_f32_16x16x32_bf16(af, bf, facc, 0, 0, 0);
        }
        if (m < 10) {
            float bias2 = bp[m];
#pragma unroll
            for (int reg = 0; reg < 4; reg++) {
                int row = rt * 16 + quad * 4 + reg;
                out[row * 10 + m] = sigmoidf_(facc[reg] + bias2);
            }
        }
    }
}

extern "C" void kernel_launch(void* const* d_in, const int* in_sizes, int n_in,
                              void* d_out, int out_size, void* d_ws, size_t ws_size,
                              hipStream_t stream) {
    const int*   code = (const int*)d_in[0];
    const int*   q    = (const int*)d_in[1];
    const int*   r    = (const int*)d_in[2];
    const float* EN   = (const float*)d_in[3];
    const float* EP   = (const float*)d_in[4];
    const float* Wpt  = (const float*)d_in[5];
    const float* bpt  = (const float*)d_in[6];
    const float* Watt = (const float*)d_in[7];
    const float* Kemb = (const float*)d_in[9];
    const float* Mk   = (const float*)d_in[10];
    const float* Mv0  = (const float*)d_in[11];
    const float* Vemb = (const float*)d_in[12];
    const float* We   = (const float*)d_in[13];
    const float* be   = (const float*)d_in[14];
    const float* Wa   = (const float*)d_in[15];
    const float* ba   = (const float*)d_in[16];
    const float* Wf   = (const float*)d_in[17];
    const float* bf_  = (const float*)d_in[18];
    const float* Wp   = (const float*)d_in[19];
    const float* bp   = (const float*)d_in[20];

    char* ws = (char*)d_ws;
    size_t off = 0;
    auto alloc = [&](size_t bytes) { void* p = ws + off; off = (off + bytes + 255) & ~255UL; return p; };
    u8*    PS8    = (u8*)alloc(10002UL * 384);
    u8*    PE8    = (u8*)alloc(10002UL * 384);
    u8*    PP8    = (u8*)alloc(10002UL * 384);
    u8*    EN8    = (u8*)alloc(10002UL * 128);
    u8*    EP8    = (u8*)alloc(10002UL * 128);
    u16*   WeaT   = (u16*)alloc(256UL * 512 * 2);
    u16*   WfT    = (u16*)alloc(128UL * 256 * 2);
    u16*   WpT    = (u16*)alloc(16UL * 128 * 2);
    float* attn   = (float*)alloc(16UL * 128 * 128 * 4);   // [b][l][p]
    u16*   vA     = (u16*)alloc(2048UL * 512 * 2);         // [Vemb[r] ; code_vec] bf16
    u16*   fA     = (u16*)alloc(2048UL * 256 * 2);         // [read ; Kemb[q]] bf16
    float* eb     = (float*)alloc(2048UL * 128 * 4);
    float* ab     = (float*)alloc(2048UL * 128 * 4);
    float* wsmall = (float*)alloc(101UL * 64 * 4);

    k_prep<<<3013, 256, 0, stream>>>(EN, EP, Wpt, bpt, We, Wa, Wf, Wp, Kemb, Mk,
                                     EN8, EP8, WeaT, WfT, WpT, wsmall, PS8, PE8, PP8);
    k_cwsm<<<2048, 256, 0, stream>>>(code, PS8, PE8, PP8, Watt, attn);
    k_cv<<<2048, 256, 0, stream>>>(code, attn, EN8, EP8, r, q, Vemb, Kemb, vA, fA);
    k_eawM<<<512, 256, 0, stream>>>(vA, WeaT, be, ba, eb, ab);
    k_scan<<<256, 64, 0, stream>>>(Mv0, eb, ab, wsmall, q, fA);
    k_outfin<<<128, 512, 0, stream>>>(fA, WfT, bf_, WpT, bp, (float*)d_out);
}